// Round 9
// baseline (171.417 us; speedup 1.0000x reference)
//
#include <hip/hip_runtime.h>

#define AGENT __HIP_MEMORY_SCOPE_AGENT

constexpr int TD = 9, TDP = 12, DIN = 135;
constexpr int CAPD = 64;                   // CSR bucket capacity (max in-degree Poisson(10) << 64)
constexpr int CAP3 = 256, CAP2 = 1024, CAP1 = 4096;
constexpr int NBM = 160;                   // k_mid grid: 160 blocks (<=256 CUs -> co-resident)
constexpr int LSTRIDE = 32;                // 128B spacing for sync cells
constexpr int NGRP = 16;                   // arrival tree: 16 groups x 10
constexpr int GSZ = NBM / NGRP;            // 10
constexpr int NSET = 8;                    // rotating barrier sets
constexpr int NLINE = 16;                  // release lines (10 pollers each)
constexpr int PB = 8;                      // nodes per block-group in h0proj

struct P {
  const float* x; const int* src; const int* dst; int N; int E;
  const float *W_in,*b_in,*g1W,*g1as,*g1ad,*g1b,*g2W,*g2as,*g2ad,*g2b,*g3W,*g3as,*g3ad,*g3b;
  const float *r1W,*r1b,*r2W,*r2b,*r3W,*r3b,*n1g,*n1b,*n2g,*n2b,*n3g,*n3b;
  const float *tw,*c1W,*c1b,*clg,*clb,*c2W,*c2b;
  float* tp;
  int *deg, *bk;                         // CSR: deg[N], bk[N*CAPD] (raw src ids)
  int *m3,*m2,*m1,*list3,*list2,*list1,*cnts;  // cnts[0..2]=c3/c2/c1, [8]=simsum(f32)
  int *barc,*barr,*barg;
  float *h0,*hh1,*es1,*ed1,*h1,*hh2,*es2,*ed2,*h2,*hh3,*es3,*ed3,*h3;
  float* dout;
};

__device__ __forceinline__ float lrelu(float v) { return v >= 0.f ? v : 0.2f * v; }

// MALL-coherent relaxed stores; readers only normal-load these lines in LATER phases.
__device__ __forceinline__ void stg(float* pp, float v) { __hip_atomic_store(pp, v, __ATOMIC_RELAXED, AGENT); }
__device__ __forceinline__ void stg(int* pp, int v)   { __hip_atomic_store(pp, v, __ATOMIC_RELAXED, AGENT); }

__device__ __forceinline__ void claim_node(int v, int* __restrict__ m, int* __restrict__ list,
                                           int* __restrict__ cnt, int cap) {
  if (atomicCAS(&m[v], -1, -2) == -1) {
    int pos = atomicAdd(cnt, 1);
    if (pos < cap) { stg(&list[pos], v); stg(&m[v], pos); } else { stg(&m[v], -3); }
  }
}

// Fence-free 160-block tree barrier (16 groups x 10 + root; rotating sets; 16 release lines).
__device__ __forceinline__ void mid_barrier(const P& p, int& lgen, int* amroot_s) {
  __syncthreads();
  int g = lgen + 1;
  if (threadIdx.x == 0) {
    *amroot_s = 0;
    int* gc = &p.barc[(((g & (NSET - 1)) * NGRP) + (blockIdx.x & (NGRP - 1))) * LSTRIDE];
    if (__hip_atomic_fetch_add(gc, 1, __ATOMIC_RELAXED, AGENT) == GSZ - 1) {
      int* rc = &p.barr[(g & (NSET - 1)) * LSTRIDE];
      if (__hip_atomic_fetch_add(rc, 1, __ATOMIC_RELAXED, AGENT) == NGRP - 1) *amroot_s = 1;
    }
  }
  __syncthreads();
  if (*amroot_s) {
    if (threadIdx.x < NLINE)
      __hip_atomic_store(&p.barg[threadIdx.x * LSTRIDE], g, __ATOMIC_RELAXED, AGENT);
  } else if (threadIdx.x == 0) {
    int* line = &p.barg[(blockIdx.x & (NLINE - 1)) * LSTRIDE];
    while (__hip_atomic_load(line, __ATOMIC_RELAXED, AGENT) < g)
      __builtin_amdgcn_s_sleep(1);
  }
  __syncthreads();
  lgen = g;
}

// clear maps/deg/counters/barrier cells; pack tp = x[:,126..134] padded to 12 floats
__global__ void k_prep(P p) {
  int gt = blockIdx.x * blockDim.x + threadIdx.x;
  int GT = gridDim.x * blockDim.x;
  int n3 = 3 * p.N;
  int4* mv = (int4*)p.m3;
  int4 neg = make_int4(-1, -1, -1, -1);
  int nv = n3 >> 2;
  for (int i = gt; i < nv; i += GT) mv[i] = neg;
  for (int i = (nv << 2) + gt; i < n3; i += GT) p.m3[i] = -1;
  int4* dv = (int4*)p.deg;
  int4 z4 = make_int4(0, 0, 0, 0);
  int ndv = p.N >> 2;
  for (int i = gt; i < ndv; i += GT) dv[i] = z4;
  for (int i = (ndv << 2) + gt; i < p.N; i += GT) p.deg[i] = 0;
  if (gt < 64) p.cnts[gt] = 0;
  for (int i = gt; i < NSET * NGRP * LSTRIDE; i += GT) p.barc[i] = 0;
  for (int i = gt; i < NSET * LSTRIDE; i += GT) p.barr[i] = 0;
  for (int i = gt; i < NLINE * LSTRIDE; i += GT) p.barg[i] = 0;
  int total = p.N * TDP;
  for (int i = gt; i < total; i += GT) {
    int v = i / TDP, k = i - v * TDP;
    p.tp[i] = (k < TD) ? p.x[(size_t)v * DIN + (DIN - TD) + k] : 0.f;
  }
}

// single E-pass: cosine-sim + CSR scatter (deg/bk) + claim S3 = {0} U N_in(0)
__global__ void k_scan(P p) {
  __shared__ float wred[4];
  int tid = threadIdx.x;
  int gt = blockIdx.x * blockDim.x + tid, GT = gridDim.x * blockDim.x;
  if (gt == 0) claim_node(0, p.m3, p.list3, &p.cnts[0], CAP3);
  const float4* t4 = (const float4*)p.tp;
  float local = 0.f;
  auto edge_proc = [&](int s, int d) {
    int slot = atomicAdd(&p.deg[d], 1);
    if (slot < CAPD) p.bk[(size_t)d * CAPD + slot] = s;   // read next kernel (boundary coherence)
    if (d == 0) claim_node(s, p.m3, p.list3, &p.cnts[0], CAP3);
    float4 a0 = t4[s * 3], a1 = t4[s * 3 + 1], a2 = t4[s * 3 + 2];
    float4 b0 = t4[d * 3], b1 = t4[d * 3 + 1], b2 = t4[d * 3 + 2];
    float dot = a0.x*b0.x + a0.y*b0.y + a0.z*b0.z + a0.w*b0.w
              + a1.x*b1.x + a1.y*b1.y + a1.z*b1.z + a1.w*b1.w
              + a2.x*b2.x;
    float na = a0.x*a0.x + a0.y*a0.y + a0.z*a0.z + a0.w*a0.w
             + a1.x*a1.x + a1.y*a1.y + a1.z*a1.z + a1.w*a1.w
             + a2.x*a2.x;
    float nb = b0.x*b0.x + b0.y*b0.y + b0.z*b0.z + b0.w*b0.w
             + b1.x*b1.x + b1.y*b1.y + b1.z*b1.z + b1.w*b1.w
             + b2.x*b2.x;
    local += dot / (fmaxf(sqrtf(na), 1e-8f) * fmaxf(sqrtf(nb), 1e-8f));
  };
  int nq4 = p.E >> 2;
  const int4* s4p = (const int4*)p.src;
  const int4* d4p = (const int4*)p.dst;
  for (int q = gt; q < nq4; q += GT) {
    int4 s4 = s4p[q], d4 = d4p[q];
    edge_proc(s4.x, d4.x); edge_proc(s4.y, d4.y); edge_proc(s4.z, d4.z); edge_proc(s4.w, d4.w);
  }
  for (int e = (nq4 << 2) + gt; e < p.E; e += GT) edge_proc(p.src[e], p.dst[e]);
  for (int off = 32; off > 0; off >>= 1) local += __shfl_down(local, off, 64);
  if ((tid & 63) == 0) wred[tid >> 6] = local;
  __syncthreads();
  if (tid == 0) atomicAdd((float*)&p.cnts[8], wred[0] + wred[1] + wred[2] + wred[3]);
}

// GAT layer over compacted dst set; bucket = CSR (by node id). stg for all outputs.
template <int C, int ONEXT>
__device__ void gat_dev(const P& p, int nq, const int* lst, const int* mPrev,
                        const float* hh, const float* es, const float* ed, const float* hres,
                        const float* gb, const float* rW, const float* rb,
                        const float* ng, const float* nbv, float scale,
                        float* hout, const float* Wn, const float* avn, const float* bvn,
                        float* hhn, float* esn, float* edn,
                        float* elog, int* eposs, float* ev_s, float* sh,
                        float* hres_s, float* shln, float* psn, float* pdn, float* sc2) {
  const int Wd = 4 * C, R = Wd / 256;
  int tid = threadIdx.x;
  for (int q = blockIdx.x; q < nq; q += gridDim.x) {
    int v = lst[q];
    int sp = mPrev[v];
    int nb = min(p.deg[v], CAPD);
    for (int j = tid; j < nb; j += 256) {
      int pu = mPrev[p.bk[(size_t)v * CAPD + j]];
      eposs[j] = pu;
      const float* ep = &es[(size_t)pu * 4];
      elog[0 * CAPD + j] = ep[0]; elog[1 * CAPD + j] = ep[1];
      elog[2 * CAPD + j] = ep[2]; elog[3 * CAPD + j] = ep[3];
    }
    if (tid < 4) { ev_s[tid] = es[(size_t)sp * 4 + tid]; ev_s[4 + tid] = ed[(size_t)sp * 4 + tid]; }
    for (int k = tid; k < 128; k += 256) hres_s[k] = hres[(size_t)sp * 128 + k];
    __syncthreads();
#pragma unroll
    for (int r = 0; r < R; r++) {
      int w = r * 256 + tid, a = w / C;
      float edv = ev_s[4 + a];
      float eself = lrelu(ev_s[a] + edv);
      float mx = eself;
      for (int j = 0; j < nb; j++) mx = fmaxf(mx, lrelu(elog[a * CAPD + j] + edv));
      float den = __expf(eself - mx);
      for (int j = 0; j < nb; j++) den += __expf(lrelu(elog[a * CAPD + j] + edv) - mx);
      float rden = 1.f / (den + 1e-16f);
      float s = __expf(eself - mx) * rden * hh[(size_t)sp * Wd + w];
      for (int j = 0; j < nb; j++)
        s += __expf(lrelu(elog[a * CAPD + j] + edv) - mx) * rden * hh[(size_t)eposs[j] * Wd + w];
      sh[w] = s;
    }
    __syncthreads();
    float val = 0.f;
    if (tid < C) {
      float g = 0.25f * (sh[tid] + sh[C + tid] + sh[2 * C + tid] + sh[3 * C + tid]) + gb[tid];
      g *= scale;
      g = fmaxf(g, 0.f);
      float rr = rb[tid];
      for (int k = 0; k < 128; k++) rr += hres_s[k] * rW[(size_t)k * C + tid];
      val = g + rr;
      shln[tid] = val;
    }
    __syncthreads();
    if (tid == 0) {
      float s1 = 0.f, s2 = 0.f;
      for (int k = 0; k < C; k++) { float u = shln[k]; s1 += u; s2 += u * u; }
      float mu = s1 / (float)C;
      sc2[0] = mu;
      sc2[1] = rsqrtf(fmaxf(s2 / (float)C - mu * mu, 0.f) + 1e-5f);
    }
    __syncthreads();
    if (tid < C) {
      float o = (val - sc2[0]) * sc2[1] * ng[tid] + nbv[tid];
      stg(&hout[(size_t)q * C + tid], o);
      shln[tid] = o;
    }
    __syncthreads();
    if (ONEXT > 0) {
      for (int j = tid; j < ONEXT; j += 256) {
        float a2 = 0.f;
        for (int k = 0; k < C; k++) a2 += shln[k] * Wn[(size_t)k * ONEXT + j];
        stg(&hhn[(size_t)q * ONEXT + j], a2);
        psn[j] = a2 * avn[j]; pdn[j] = a2 * bvn[j];
      }
      __syncthreads();
      if (tid < 8) {
        const int CN = ONEXT / 4; int a = tid & 3;
        const float* pr = (tid < 4) ? psn : pdn;
        float s = 0.f;
        for (int cc = 0; cc < CN; cc++) s += pr[a * CN + cc];
        stg(&(tid < 4 ? esn : edn)[(size_t)q * 4 + a], s);
      }
      __syncthreads();
    }
  }
}

__global__ __launch_bounds__(256) void k_mid(P p) {
  __shared__ float xs8[PB][DIN];
  __shared__ float hs8[PB][128];
  __shared__ float psn[512], pdn[512];
  __shared__ int   vid8[PB];
  __shared__ float elog[4 * CAPD];
  __shared__ int   eposs[CAPD];
  __shared__ float ev_s[8], sc2[2];
  __shared__ float sh[512], hres_s[128], shln[128];
  __shared__ float zcl[64];
  __shared__ int   amroot_s;

  int tid = threadIdx.x, bid = blockIdx.x;
  int lgen = 0;
  float scale = 1.1f + 0.1f * p.tw[0] *
      __int_as_float(__hip_atomic_load(&p.cnts[8], __ATOMIC_RELAXED, AGENT)) / (float)p.E;

  // ---- a: expand S3 -> S2 (claims via CSR buckets of list3) ----
  {
    int c3 = min(__hip_atomic_load(&p.cnts[0], __ATOMIC_RELAXED, AGENT), CAP3);
    for (int q = bid; q < c3; q += NBM) {
      int v = p.list3[q];
      if (tid == 0) claim_node(v, p.m2, p.list2, &p.cnts[1], CAP2);
      int nb = min(p.deg[v], CAPD);
      for (int j = tid; j < nb; j += 256)
        claim_node(p.bk[(size_t)v * CAPD + j], p.m2, p.list2, &p.cnts[1], CAP2);
    }
  }
  mid_barrier(p, lgen, &amroot_s);

  // ---- b: expand S2 -> S1 ----
  {
    int c2 = min(__hip_atomic_load(&p.cnts[1], __ATOMIC_RELAXED, AGENT), CAP2);
    for (int q = bid; q < c2; q += NBM) {
      int v = p.list2[q];
      if (tid == 0) claim_node(v, p.m1, p.list1, &p.cnts[2], CAP1);
      int nb = min(p.deg[v], CAPD);
      for (int j = tid; j < nb; j += 256)
        claim_node(p.bk[(size_t)v * CAPD + j], p.m1, p.list1, &p.cnts[2], CAP1);
    }
  }
  mid_barrier(p, lgen, &amroot_s);

  // ---- c: h0 = x@W_in+b_in ; hh1 = h0@g1W ; es1/ed1  (PB nodes per group) ----
  {
    int c1 = min(__hip_atomic_load(&p.cnts[2], __ATOMIC_RELAXED, AGENT), CAP1);
    int ngp = (c1 + PB - 1) / PB;
    for (int g = bid; g < ngp; g += NBM) {
      int base = g * PB, nn = min(PB, c1 - base);
      if (tid < nn) vid8[tid] = p.list1[base + tid];
      __syncthreads();
      for (int idx = tid; idx < nn * DIN; idx += 256) {
        int u = idx / DIN, k = idx - u * DIN;
        xs8[u][k] = p.x[(size_t)vid8[u] * DIN + k];
      }
      __syncthreads();
      if (tid < 128) {
        float a[PB]; float bi = p.b_in[tid];
#pragma unroll
        for (int u = 0; u < PB; u++) a[u] = bi;
        for (int k = 0; k < DIN; k++) {
          float w = p.W_in[(size_t)k * 128 + tid];
#pragma unroll
          for (int u = 0; u < PB; u++) a[u] += xs8[u][k] * w;
        }
#pragma unroll
        for (int u = 0; u < PB; u++) {
          hs8[u][tid] = a[u];
          if (u < nn) stg(&p.h0[(size_t)(base + u) * 128 + tid], a[u]);
        }
      }
      __syncthreads();
      float bsv[2][PB];
#pragma unroll
      for (int jj = 0; jj < 2; jj++) {
        int j = jj * 256 + tid;
        float b[PB];
#pragma unroll
        for (int u = 0; u < PB; u++) b[u] = 0.f;
        for (int k = 0; k < 128; k++) {
          float w = p.g1W[(size_t)k * 512 + j];
#pragma unroll
          for (int u = 0; u < PB; u++) b[u] += hs8[u][k] * w;
        }
#pragma unroll
        for (int u = 0; u < PB; u++) {
          bsv[jj][u] = b[u];
          if (u < nn) stg(&p.hh1[(size_t)(base + u) * 512 + j], b[u]);
        }
      }
      for (int u = 0; u < nn; u++) {
#pragma unroll
        for (int jj = 0; jj < 2; jj++) {
          int j = jj * 256 + tid;
          psn[j] = bsv[jj][u] * p.g1as[j];
          pdn[j] = bsv[jj][u] * p.g1ad[j];
        }
        __syncthreads();
        if (tid < 8) {
          int a = tid & 3;
          const float* pr = (tid < 4) ? psn : pdn;
          float s = 0.f;
          for (int cc = 0; cc < 128; cc++) s += pr[a * 128 + cc];
          stg(&(tid < 4 ? p.es1 : p.ed1)[(size_t)(base + u) * 4 + a], s);
        }
        __syncthreads();
      }
    }
  }
  mid_barrier(p, lgen, &amroot_s);

  // ---- d: GAT1 over S2 (+ fused proj2) ----
  {
    int c2 = min(__hip_atomic_load(&p.cnts[1], __ATOMIC_RELAXED, AGENT), CAP2);
    gat_dev<128, 512>(p, c2, p.list2, p.m1, p.hh1, p.es1, p.ed1, p.h0,
                      p.g1b, p.r1W, p.r1b, p.n1g, p.n1b, scale,
                      p.h1, p.g2W, p.g2as, p.g2ad, p.hh2, p.es2, p.ed2,
                      elog, eposs, ev_s, sh, hres_s, shln, psn, pdn, sc2);
  }
  mid_barrier(p, lgen, &amroot_s);

  // ---- e: GAT2 over S3 (+ fused proj3) ----
  {
    int c3 = min(__hip_atomic_load(&p.cnts[0], __ATOMIC_RELAXED, AGENT), CAP3);
    gat_dev<128, 256>(p, c3, p.list3, p.m2, p.hh2, p.es2, p.ed2, p.h1,
                      p.g2b, p.r2W, p.r2b, p.n2g, p.n2b, scale,
                      p.h2, p.g3W, p.g3as, p.g3ad, p.hh3, p.es3, p.ed3,
                      elog, eposs, ev_s, sh, hres_s, shln, psn, pdn, sc2);
  }
  mid_barrier(p, lgen, &amroot_s);

  // ---- f: GAT3 for node 0 + classifier (block 0 only) ----
  if (bid == 0) {
    int zero = 0;
    gat_dev<64, 0>(p, 1, &zero /* dst list = {0}; lane-uniform */, p.m3,
                   p.hh3, p.es3, p.ed3, p.h2,
                   p.g3b, p.r3W, p.r3b, p.n3g, p.n3b, 1.f,
                   p.h3, nullptr, nullptr, nullptr, nullptr, nullptr, nullptr,
                   elog, eposs, ev_s, sh, hres_s, shln, psn, pdn, sc2);
    if (tid < 64) {
      float az = p.c1b[tid];
      for (int k = 0; k < 64; k++) az += shln[k] * p.c1W[k * 64 + tid];
      zcl[tid] = fmaxf(az, 0.f);
    }
    __syncthreads();
    if (tid == 0) {
      float s1 = 0.f, s2 = 0.f;
      for (int k = 0; k < 64; k++) { float u = zcl[k]; s1 += u; s2 += u * u; }
      float mu = s1 / 64.f;
      float rstd = rsqrtf(fmaxf(s2 / 64.f - mu * mu, 0.f) + 1e-5f);
      float o0 = p.c2b[0], o1 = p.c2b[1];
      for (int k = 0; k < 64; k++) {
        float zn = (zcl[k] - mu) * rstd * p.clg[k] + p.clb[k];
        o0 += zn * p.c2W[k * 2 + 0];
        o1 += zn * p.c2W[k * 2 + 1];
      }
      p.dout[0] = o0; p.dout[1] = o1;
    }
  }
}

extern "C" void kernel_launch(void* const* d_in, const int* in_sizes, int n_in,
                              void* d_out, int out_size, void* d_ws, size_t ws_size,
                              hipStream_t stream) {
  P p;
  p.x = (const float*)d_in[0];
  const int* ei = (const int*)d_in[1];
  p.N = in_sizes[0] / DIN;
  p.E = in_sizes[1] / 2;
  p.src = ei; p.dst = ei + p.E;
  p.W_in = (const float*)d_in[3]; p.b_in = (const float*)d_in[4];
  p.g1W = (const float*)d_in[5]; p.g1as = (const float*)d_in[6]; p.g1ad = (const float*)d_in[7]; p.g1b = (const float*)d_in[8];
  p.g2W = (const float*)d_in[9]; p.g2as = (const float*)d_in[10]; p.g2ad = (const float*)d_in[11]; p.g2b = (const float*)d_in[12];
  p.g3W = (const float*)d_in[13]; p.g3as = (const float*)d_in[14]; p.g3ad = (const float*)d_in[15]; p.g3b = (const float*)d_in[16];
  p.r1W = (const float*)d_in[17]; p.r1b = (const float*)d_in[18];
  p.r2W = (const float*)d_in[19]; p.r2b = (const float*)d_in[20];
  p.r3W = (const float*)d_in[21]; p.r3b = (const float*)d_in[22];
  p.n1g = (const float*)d_in[23]; p.n1b = (const float*)d_in[24];
  p.n2g = (const float*)d_in[25]; p.n2b = (const float*)d_in[26];
  p.n3g = (const float*)d_in[27]; p.n3b = (const float*)d_in[28];
  p.tw  = (const float*)d_in[29];
  p.c1W = (const float*)d_in[30]; p.c1b = (const float*)d_in[31];
  p.clg = (const float*)d_in[32]; p.clb = (const float*)d_in[33];
  p.c2W = (const float*)d_in[34]; p.c2b = (const float*)d_in[35];
  p.dout = (float*)d_out;

  char* B = (char*)d_ws;
  size_t off = 0;
  auto take = [&](size_t nbytes) -> char* {
    char* r = B + off;
    off += (nbytes + 255) & ~(size_t)255;
    return r;
  };
  p.cnts  = (int*)take(256);
  p.barc  = (int*)take((size_t)NSET * NGRP * LSTRIDE * 4);
  p.barr  = (int*)take((size_t)NSET * LSTRIDE * 4);
  p.barg  = (int*)take((size_t)NLINE * LSTRIDE * 4);
  p.m3    = (int*)take((size_t)3 * p.N * 4);
  p.m2 = p.m3 + p.N; p.m1 = p.m2 + p.N;
  p.tp    = (float*)take((size_t)p.N * TDP * 4);
  p.deg   = (int*)take((size_t)p.N * 4);
  p.bk    = (int*)take((size_t)p.N * CAPD * 4);
  p.list3 = (int*)take(CAP3 * 4);
  p.list2 = (int*)take(CAP2 * 4);
  p.list1 = (int*)take(CAP1 * 4);
  p.h0    = (float*)take((size_t)CAP1 * 128 * 4);
  p.hh1   = (float*)take((size_t)CAP1 * 512 * 4);
  p.es1   = (float*)take((size_t)CAP1 * 16);
  p.ed1   = (float*)take((size_t)CAP1 * 16);
  p.h1    = (float*)take((size_t)CAP2 * 128 * 4);
  p.hh2   = (float*)take((size_t)CAP2 * 512 * 4);
  p.es2   = (float*)take((size_t)CAP2 * 16);
  p.ed2   = (float*)take((size_t)CAP2 * 16);
  p.h2    = (float*)take((size_t)CAP3 * 128 * 4);
  p.hh3   = (float*)take((size_t)CAP3 * 256 * 4);
  p.es3   = (float*)take((size_t)CAP3 * 16);
  p.ed3   = (float*)take((size_t)CAP3 * 16);
  p.h3    = (float*)take(64 * 4);

  k_prep<<<1024, 256, 0, stream>>>(p);
  k_scan<<<1024, 256, 0, stream>>>(p);
  k_mid<<<NBM, 256, 0, stream>>>(p);
}

// Round 10
// 134.937 us; speedup vs baseline: 1.2704x; 1.2704x over previous
//
#include <hip/hip_runtime.h>

#define AGENT __HIP_MEMORY_SCOPE_AGENT

constexpr int TD = 9, TDP = 12, DIN = 135;
constexpr int CAPD = 64;                   // CSR bucket capacity (max in-degree Poisson(10) << 64)
constexpr int CAP3 = 256, CAP2 = 1024, CAP1 = 4096;
constexpr int NBM = 512;                   // k_mid grid: 512 blocks, launch_bounds(256,2) -> co-resident (R5-proven)
constexpr int LSTRIDE = 32;                // 128B spacing for sync cells
constexpr int NGRP = 16;                   // arrival tree: 16 groups x 32
constexpr int GSZ = NBM / NGRP;            // 32
constexpr int NSET = 8;                    // rotating barrier sets
constexpr int NLINE = 64;                  // release lines (8 pollers each)
constexpr int PB = 8;                      // nodes per block-group in h0proj

struct P {
  const float* x; const int* src; const int* dst; int N; int E;
  const float *W_in,*b_in,*g1W,*g1as,*g1ad,*g1b,*g2W,*g2as,*g2ad,*g2b,*g3W,*g3as,*g3ad,*g3b;
  const float *r1W,*r1b,*r2W,*r2b,*r3W,*r3b,*n1g,*n1b,*n2g,*n2b,*n3g,*n3b;
  const float *tw,*c1W,*c1b,*clg,*clb,*c2W,*c2b;
  float* tp;
  int *deg, *bk;                         // CSR: deg[N], bk[N*CAPD] (raw src ids)
  int *m3,*m2,*m1,*list3,*list2,*list1,*cnts;  // cnts[0..2]=c3/c2/c1, [8]=simsum(f32)
  int *barc,*barr,*barg;
  float *h0,*hh1,*es1,*ed1,*h1,*hh2,*es2,*ed2,*h2,*hh3,*es3,*ed3,*h3;
  float* dout;
};

__device__ __forceinline__ float lrelu(float v) { return v >= 0.f ? v : 0.2f * v; }

// MALL-coherent relaxed stores; readers only normal-load these lines in LATER phases.
__device__ __forceinline__ void stg(float* pp, float v) { __hip_atomic_store(pp, v, __ATOMIC_RELAXED, AGENT); }
__device__ __forceinline__ void stg(int* pp, int v)   { __hip_atomic_store(pp, v, __ATOMIC_RELAXED, AGENT); }

__device__ __forceinline__ void claim_node(int v, int* __restrict__ m, int* __restrict__ list,
                                           int* __restrict__ cnt, int cap) {
  if (atomicCAS(&m[v], -1, -2) == -1) {
    int pos = atomicAdd(cnt, 1);
    if (pos < cap) { stg(&list[pos], v); stg(&m[v], pos); } else { stg(&m[v], -3); }
  }
}

// Fence-free 512-block tree barrier (16 groups x 32 + root; rotating sets; 64 release lines).
__device__ __forceinline__ void mid_barrier(const P& p, int& lgen, int* amroot_s) {
  __syncthreads();
  int g = lgen + 1;
  if (threadIdx.x == 0) {
    *amroot_s = 0;
    int* gc = &p.barc[(((g & (NSET - 1)) * NGRP) + (blockIdx.x & (NGRP - 1))) * LSTRIDE];
    if (__hip_atomic_fetch_add(gc, 1, __ATOMIC_RELAXED, AGENT) == GSZ - 1) {
      int* rc = &p.barr[(g & (NSET - 1)) * LSTRIDE];
      if (__hip_atomic_fetch_add(rc, 1, __ATOMIC_RELAXED, AGENT) == NGRP - 1) *amroot_s = 1;
    }
  }
  __syncthreads();
  if (*amroot_s) {
    if (threadIdx.x < NLINE)
      __hip_atomic_store(&p.barg[threadIdx.x * LSTRIDE], g, __ATOMIC_RELAXED, AGENT);
  } else if (threadIdx.x == 0) {
    int* line = &p.barg[(blockIdx.x & (NLINE - 1)) * LSTRIDE];
    while (__hip_atomic_load(line, __ATOMIC_RELAXED, AGENT) < g)
      __builtin_amdgcn_s_sleep(8);
  }
  __syncthreads();
  lgen = g;
}

// clear maps/deg/counters/barrier cells; pack tp = x[:,126..134] padded to 12 floats
__global__ void k_prep(P p) {
  int gt = blockIdx.x * blockDim.x + threadIdx.x;
  int GT = gridDim.x * blockDim.x;
  int n3 = 3 * p.N;
  int4* mv = (int4*)p.m3;
  int4 neg = make_int4(-1, -1, -1, -1);
  int nv = n3 >> 2;
  for (int i = gt; i < nv; i += GT) mv[i] = neg;
  for (int i = (nv << 2) + gt; i < n3; i += GT) p.m3[i] = -1;
  int4* dv = (int4*)p.deg;
  int4 z4 = make_int4(0, 0, 0, 0);
  int ndv = p.N >> 2;
  for (int i = gt; i < ndv; i += GT) dv[i] = z4;
  for (int i = (ndv << 2) + gt; i < p.N; i += GT) p.deg[i] = 0;
  if (gt < 64) p.cnts[gt] = 0;
  for (int i = gt; i < NSET * NGRP * LSTRIDE; i += GT) p.barc[i] = 0;
  for (int i = gt; i < NSET * LSTRIDE; i += GT) p.barr[i] = 0;
  for (int i = gt; i < NLINE * LSTRIDE; i += GT) p.barg[i] = 0;
  int total = p.N * TDP;
  for (int i = gt; i < total; i += GT) {
    int v = i / TDP, k = i - v * TDP;
    p.tp[i] = (k < TD) ? p.x[(size_t)v * DIN + (DIN - TD) + k] : 0.f;
  }
}

// single E-pass: cosine-sim + CSR scatter (deg/bk) + claim S3 = {0} U N_in(0)
__global__ void k_scan(P p) {
  __shared__ float wred[4];
  int tid = threadIdx.x;
  int gt = blockIdx.x * blockDim.x + tid, GT = gridDim.x * blockDim.x;
  if (gt == 0) claim_node(0, p.m3, p.list3, &p.cnts[0], CAP3);
  const float4* t4 = (const float4*)p.tp;
  float local = 0.f;
  auto edge_proc = [&](int s, int d) {
    int slot = atomicAdd(&p.deg[d], 1);
    if (slot < CAPD) p.bk[(size_t)d * CAPD + slot] = s;   // read next kernel (boundary coherence)
    if (d == 0) claim_node(s, p.m3, p.list3, &p.cnts[0], CAP3);
    float4 a0 = t4[s * 3], a1 = t4[s * 3 + 1], a2 = t4[s * 3 + 2];
    float4 b0 = t4[d * 3], b1 = t4[d * 3 + 1], b2 = t4[d * 3 + 2];
    float dot = a0.x*b0.x + a0.y*b0.y + a0.z*b0.z + a0.w*b0.w
              + a1.x*b1.x + a1.y*b1.y + a1.z*b1.z + a1.w*b1.w
              + a2.x*b2.x;
    float na = a0.x*a0.x + a0.y*a0.y + a0.z*a0.z + a0.w*a0.w
             + a1.x*a1.x + a1.y*a1.y + a1.z*a1.z + a1.w*a1.w
             + a2.x*a2.x;
    float nb = b0.x*b0.x + b0.y*b0.y + b0.z*b0.z + b0.w*b0.w
             + b1.x*b1.x + b1.y*b1.y + b1.z*b1.z + b1.w*b1.w
             + b2.x*b2.x;
    local += dot / (fmaxf(sqrtf(na), 1e-8f) * fmaxf(sqrtf(nb), 1e-8f));
  };
  int nq4 = p.E >> 2;
  const int4* s4p = (const int4*)p.src;
  const int4* d4p = (const int4*)p.dst;
  for (int q = gt; q < nq4; q += GT) {
    int4 s4 = s4p[q], d4 = d4p[q];
    edge_proc(s4.x, d4.x); edge_proc(s4.y, d4.y); edge_proc(s4.z, d4.z); edge_proc(s4.w, d4.w);
  }
  for (int e = (nq4 << 2) + gt; e < p.E; e += GT) edge_proc(p.src[e], p.dst[e]);
  for (int off = 32; off > 0; off >>= 1) local += __shfl_down(local, off, 64);
  if ((tid & 63) == 0) wred[tid >> 6] = local;
  __syncthreads();
  if (tid == 0) atomicAdd((float*)&p.cnts[8], wred[0] + wred[1] + wred[2] + wred[3]);
}

// GAT layer over compacted dst set; bucket = CSR (by node id). stg for all outputs.
template <int C, int ONEXT>
__device__ void gat_dev(const P& p, int nq, const int* lst, const int* mPrev,
                        const float* hh, const float* es, const float* ed, const float* hres,
                        const float* gb, const float* rW, const float* rb,
                        const float* ng, const float* nbv, float scale,
                        float* hout, const float* Wn, const float* avn, const float* bvn,
                        float* hhn, float* esn, float* edn,
                        float* elog, int* eposs, float* ev_s, float* sh,
                        float* hres_s, float* shln, float* psn, float* pdn, float* sc2) {
  const int Wd = 4 * C, R = Wd / 256;
  int tid = threadIdx.x;
  for (int q = blockIdx.x; q < nq; q += gridDim.x) {
    int v = lst[q];
    int sp = mPrev[v];
    int nb = min(p.deg[v], CAPD);
    for (int j = tid; j < nb; j += 256) {
      int pu = mPrev[p.bk[(size_t)v * CAPD + j]];
      eposs[j] = pu;
      const float* ep = &es[(size_t)pu * 4];
      elog[0 * CAPD + j] = ep[0]; elog[1 * CAPD + j] = ep[1];
      elog[2 * CAPD + j] = ep[2]; elog[3 * CAPD + j] = ep[3];
    }
    if (tid < 4) { ev_s[tid] = es[(size_t)sp * 4 + tid]; ev_s[4 + tid] = ed[(size_t)sp * 4 + tid]; }
    for (int k = tid; k < 128; k += 256) hres_s[k] = hres[(size_t)sp * 128 + k];
    __syncthreads();
#pragma unroll
    for (int r = 0; r < R; r++) {
      int w = r * 256 + tid, a = w / C;
      float edv = ev_s[4 + a];
      float eself = lrelu(ev_s[a] + edv);
      float mx = eself;
      for (int j = 0; j < nb; j++) mx = fmaxf(mx, lrelu(elog[a * CAPD + j] + edv));
      float den = __expf(eself - mx);
      for (int j = 0; j < nb; j++) den += __expf(lrelu(elog[a * CAPD + j] + edv) - mx);
      float rden = 1.f / (den + 1e-16f);
      float s = __expf(eself - mx) * rden * hh[(size_t)sp * Wd + w];
      for (int j = 0; j < nb; j++)
        s += __expf(lrelu(elog[a * CAPD + j] + edv) - mx) * rden * hh[(size_t)eposs[j] * Wd + w];
      sh[w] = s;
    }
    __syncthreads();
    float val = 0.f;
    if (tid < C) {
      float g = 0.25f * (sh[tid] + sh[C + tid] + sh[2 * C + tid] + sh[3 * C + tid]) + gb[tid];
      g *= scale;
      g = fmaxf(g, 0.f);
      float rr = rb[tid];
      for (int k = 0; k < 128; k++) rr += hres_s[k] * rW[(size_t)k * C + tid];
      val = g + rr;
      shln[tid] = val;
    }
    __syncthreads();
    if (tid == 0) {
      float s1 = 0.f, s2 = 0.f;
      for (int k = 0; k < C; k++) { float u = shln[k]; s1 += u; s2 += u * u; }
      float mu = s1 / (float)C;
      sc2[0] = mu;
      sc2[1] = rsqrtf(fmaxf(s2 / (float)C - mu * mu, 0.f) + 1e-5f);
    }
    __syncthreads();
    if (tid < C) {
      float o = (val - sc2[0]) * sc2[1] * ng[tid] + nbv[tid];
      stg(&hout[(size_t)q * C + tid], o);
      shln[tid] = o;
    }
    __syncthreads();
    if (ONEXT > 0) {
      for (int j = tid; j < ONEXT; j += 256) {
        float a2 = 0.f;
        for (int k = 0; k < C; k++) a2 += shln[k] * Wn[(size_t)k * ONEXT + j];
        stg(&hhn[(size_t)q * ONEXT + j], a2);
        psn[j] = a2 * avn[j]; pdn[j] = a2 * bvn[j];
      }
      __syncthreads();
      if (tid < 8) {
        const int CN = ONEXT / 4; int a = tid & 3;
        const float* pr = (tid < 4) ? psn : pdn;
        float s = 0.f;
        for (int cc = 0; cc < CN; cc++) s += pr[a * CN + cc];
        stg(&(tid < 4 ? esn : edn)[(size_t)q * 4 + a], s);
      }
      __syncthreads();
    }
  }
}

__global__ __launch_bounds__(256, 2) void k_mid(P p) {
  __shared__ float xs8[PB][DIN];
  __shared__ float hs8[PB][128];
  __shared__ float psn[512], pdn[512];
  __shared__ int   vid8[PB];
  __shared__ float elog[4 * CAPD];
  __shared__ int   eposs[CAPD];
  __shared__ float ev_s[8], sc2[2];
  __shared__ float sh[512], hres_s[128], shln[128];
  __shared__ float zcl[64];
  __shared__ int   amroot_s;

  int tid = threadIdx.x, bid = blockIdx.x;
  int lgen = 0;
  float scale = 1.1f + 0.1f * p.tw[0] *
      __int_as_float(__hip_atomic_load(&p.cnts[8], __ATOMIC_RELAXED, AGENT)) / (float)p.E;

  // ---- a: expand S3 -> S2 (claims via CSR buckets of list3) ----
  {
    int c3 = min(__hip_atomic_load(&p.cnts[0], __ATOMIC_RELAXED, AGENT), CAP3);
    for (int q = bid; q < c3; q += NBM) {
      int v = p.list3[q];
      if (tid == 0) claim_node(v, p.m2, p.list2, &p.cnts[1], CAP2);
      int nb = min(p.deg[v], CAPD);
      for (int j = tid; j < nb; j += 256)
        claim_node(p.bk[(size_t)v * CAPD + j], p.m2, p.list2, &p.cnts[1], CAP2);
    }
  }
  mid_barrier(p, lgen, &amroot_s);

  // ---- b: expand S2 -> S1 ----
  {
    int c2 = min(__hip_atomic_load(&p.cnts[1], __ATOMIC_RELAXED, AGENT), CAP2);
    for (int q = bid; q < c2; q += NBM) {
      int v = p.list2[q];
      if (tid == 0) claim_node(v, p.m1, p.list1, &p.cnts[2], CAP1);
      int nb = min(p.deg[v], CAPD);
      for (int j = tid; j < nb; j += 256)
        claim_node(p.bk[(size_t)v * CAPD + j], p.m1, p.list1, &p.cnts[2], CAP1);
    }
  }
  mid_barrier(p, lgen, &amroot_s);

  // ---- c: h0 = x@W_in+b_in ; hh1 = h0@g1W ; es1/ed1  (PB nodes per group) ----
  {
    int c1 = min(__hip_atomic_load(&p.cnts[2], __ATOMIC_RELAXED, AGENT), CAP1);
    int ngp = (c1 + PB - 1) / PB;
    for (int g = bid; g < ngp; g += NBM) {
      int base = g * PB, nn = min(PB, c1 - base);
      if (tid < nn) vid8[tid] = p.list1[base + tid];
      __syncthreads();
      for (int idx = tid; idx < nn * DIN; idx += 256) {
        int u = idx / DIN, k = idx - u * DIN;
        xs8[u][k] = p.x[(size_t)vid8[u] * DIN + k];
      }
      __syncthreads();
      if (tid < 128) {
        float a[PB]; float bi = p.b_in[tid];
#pragma unroll
        for (int u = 0; u < PB; u++) a[u] = bi;
        for (int k = 0; k < DIN; k++) {
          float w = p.W_in[(size_t)k * 128 + tid];
#pragma unroll
          for (int u = 0; u < PB; u++) a[u] += xs8[u][k] * w;
        }
#pragma unroll
        for (int u = 0; u < PB; u++) {
          hs8[u][tid] = a[u];
          if (u < nn) stg(&p.h0[(size_t)(base + u) * 128 + tid], a[u]);
        }
      }
      __syncthreads();
      float bsv[2][PB];
#pragma unroll
      for (int jj = 0; jj < 2; jj++) {
        int j = jj * 256 + tid;
        float b[PB];
#pragma unroll
        for (int u = 0; u < PB; u++) b[u] = 0.f;
        for (int k = 0; k < 128; k++) {
          float w = p.g1W[(size_t)k * 512 + j];
#pragma unroll
          for (int u = 0; u < PB; u++) b[u] += hs8[u][k] * w;
        }
#pragma unroll
        for (int u = 0; u < PB; u++) {
          bsv[jj][u] = b[u];
          if (u < nn) stg(&p.hh1[(size_t)(base + u) * 512 + j], b[u]);
        }
      }
      for (int u = 0; u < nn; u++) {
#pragma unroll
        for (int jj = 0; jj < 2; jj++) {
          int j = jj * 256 + tid;
          psn[j] = bsv[jj][u] * p.g1as[j];
          pdn[j] = bsv[jj][u] * p.g1ad[j];
        }
        __syncthreads();
        if (tid < 8) {
          int a = tid & 3;
          const float* pr = (tid < 4) ? psn : pdn;
          float s = 0.f;
          for (int cc = 0; cc < 128; cc++) s += pr[a * 128 + cc];
          stg(&(tid < 4 ? p.es1 : p.ed1)[(size_t)(base + u) * 4 + a], s);
        }
        __syncthreads();
      }
    }
  }
  mid_barrier(p, lgen, &amroot_s);

  // ---- d: GAT1 over S2 (+ fused proj2) ----
  {
    int c2 = min(__hip_atomic_load(&p.cnts[1], __ATOMIC_RELAXED, AGENT), CAP2);
    gat_dev<128, 512>(p, c2, p.list2, p.m1, p.hh1, p.es1, p.ed1, p.h0,
                      p.g1b, p.r1W, p.r1b, p.n1g, p.n1b, scale,
                      p.h1, p.g2W, p.g2as, p.g2ad, p.hh2, p.es2, p.ed2,
                      elog, eposs, ev_s, sh, hres_s, shln, psn, pdn, sc2);
  }
  mid_barrier(p, lgen, &amroot_s);

  // ---- e: GAT2 over S3 (+ fused proj3) ----
  {
    int c3 = min(__hip_atomic_load(&p.cnts[0], __ATOMIC_RELAXED, AGENT), CAP3);
    gat_dev<128, 256>(p, c3, p.list3, p.m2, p.hh2, p.es2, p.ed2, p.h1,
                      p.g2b, p.r2W, p.r2b, p.n2g, p.n2b, scale,
                      p.h2, p.g3W, p.g3as, p.g3ad, p.hh3, p.es3, p.ed3,
                      elog, eposs, ev_s, sh, hres_s, shln, psn, pdn, sc2);
  }
  mid_barrier(p, lgen, &amroot_s);

  // ---- f: GAT3 for node 0 + classifier (block 0 only) ----
  if (bid == 0) {
    int zero = 0;
    gat_dev<64, 0>(p, 1, &zero /* dst list = {0}; lane-uniform */, p.m3,
                   p.hh3, p.es3, p.ed3, p.h2,
                   p.g3b, p.r3W, p.r3b, p.n3g, p.n3b, 1.f,
                   p.h3, nullptr, nullptr, nullptr, nullptr, nullptr, nullptr,
                   elog, eposs, ev_s, sh, hres_s, shln, psn, pdn, sc2);
    if (tid < 64) {
      float az = p.c1b[tid];
      for (int k = 0; k < 64; k++) az += shln[k] * p.c1W[k * 64 + tid];
      zcl[tid] = fmaxf(az, 0.f);
    }
    __syncthreads();
    if (tid == 0) {
      float s1 = 0.f, s2 = 0.f;
      for (int k = 0; k < 64; k++) { float u = zcl[k]; s1 += u; s2 += u * u; }
      float mu = s1 / 64.f;
      float rstd = rsqrtf(fmaxf(s2 / 64.f - mu * mu, 0.f) + 1e-5f);
      float o0 = p.c2b[0], o1 = p.c2b[1];
      for (int k = 0; k < 64; k++) {
        float zn = (zcl[k] - mu) * rstd * p.clg[k] + p.clb[k];
        o0 += zn * p.c2W[k * 2 + 0];
        o1 += zn * p.c2W[k * 2 + 1];
      }
      p.dout[0] = o0; p.dout[1] = o1;
    }
  }
}

extern "C" void kernel_launch(void* const* d_in, const int* in_sizes, int n_in,
                              void* d_out, int out_size, void* d_ws, size_t ws_size,
                              hipStream_t stream) {
  P p;
  p.x = (const float*)d_in[0];
  const int* ei = (const int*)d_in[1];
  p.N = in_sizes[0] / DIN;
  p.E = in_sizes[1] / 2;
  p.src = ei; p.dst = ei + p.E;
  p.W_in = (const float*)d_in[3]; p.b_in = (const float*)d_in[4];
  p.g1W = (const float*)d_in[5]; p.g1as = (const float*)d_in[6]; p.g1ad = (const float*)d_in[7]; p.g1b = (const float*)d_in[8];
  p.g2W = (const float*)d_in[9]; p.g2as = (const float*)d_in[10]; p.g2ad = (const float*)d_in[11]; p.g2b = (const float*)d_in[12];
  p.g3W = (const float*)d_in[13]; p.g3as = (const float*)d_in[14]; p.g3ad = (const float*)d_in[15]; p.g3b = (const float*)d_in[16];
  p.r1W = (const float*)d_in[17]; p.r1b = (const float*)d_in[18];
  p.r2W = (const float*)d_in[19]; p.r2b = (const float*)d_in[20];
  p.r3W = (const float*)d_in[21]; p.r3b = (const float*)d_in[22];
  p.n1g = (const float*)d_in[23]; p.n1b = (const float*)d_in[24];
  p.n2g = (const float*)d_in[25]; p.n2b = (const float*)d_in[26];
  p.n3g = (const float*)d_in[27]; p.n3b = (const float*)d_in[28];
  p.tw  = (const float*)d_in[29];
  p.c1W = (const float*)d_in[30]; p.c1b = (const float*)d_in[31];
  p.clg = (const float*)d_in[32]; p.clb = (const float*)d_in[33];
  p.c2W = (const float*)d_in[34]; p.c2b = (const float*)d_in[35];
  p.dout = (float*)d_out;

  char* B = (char*)d_ws;
  size_t off = 0;
  auto take = [&](size_t nbytes) -> char* {
    char* r = B + off;
    off += (nbytes + 255) & ~(size_t)255;
    return r;
  };
  p.cnts  = (int*)take(256);
  p.barc  = (int*)take((size_t)NSET * NGRP * LSTRIDE * 4);
  p.barr  = (int*)take((size_t)NSET * LSTRIDE * 4);
  p.barg  = (int*)take((size_t)NLINE * LSTRIDE * 4);
  p.m3    = (int*)take((size_t)3 * p.N * 4);
  p.m2 = p.m3 + p.N; p.m1 = p.m2 + p.N;
  p.tp    = (float*)take((size_t)p.N * TDP * 4);
  p.deg   = (int*)take((size_t)p.N * 4);
  p.bk    = (int*)take((size_t)p.N * CAPD * 4);
  p.list3 = (int*)take(CAP3 * 4);
  p.list2 = (int*)take(CAP2 * 4);
  p.list1 = (int*)take(CAP1 * 4);
  p.h0    = (float*)take((size_t)CAP1 * 128 * 4);
  p.hh1   = (float*)take((size_t)CAP1 * 512 * 4);
  p.es1   = (float*)take((size_t)CAP1 * 16);
  p.ed1   = (float*)take((size_t)CAP1 * 16);
  p.h1    = (float*)take((size_t)CAP2 * 128 * 4);
  p.hh2   = (float*)take((size_t)CAP2 * 512 * 4);
  p.es2   = (float*)take((size_t)CAP2 * 16);
  p.ed2   = (float*)take((size_t)CAP2 * 16);
  p.h2    = (float*)take((size_t)CAP3 * 128 * 4);
  p.hh3   = (float*)take((size_t)CAP3 * 256 * 4);
  p.es3   = (float*)take((size_t)CAP3 * 16);
  p.ed3   = (float*)take((size_t)CAP3 * 16);
  p.h3    = (float*)take(64 * 4);

  k_prep<<<1024, 256, 0, stream>>>(p);
  k_scan<<<1024, 256, 0, stream>>>(p);
  k_mid<<<NBM, 256, 0, stream>>>(p);
}